// Round 9
// baseline (251.705 us; speedup 1.0000x reference)
//
#include <hip/hip_runtime.h>
#include <hip/hip_fp16.h>
#include <math.h>

#define N_NODES 50000
#define N_EDGES 800000
#define D_INF   256
#define D_HID   64
#define D_OUTF  32
#define LEAKY   0.2f

#define MT 64     // gemm1 M-tile rows
#define KB 16     // gemm1 K-step

__device__ __forceinline__ float leaky_relu(float x){ return x >= 0.f ? x : LEAKY * x; }

union H4 { __half2 h[2]; float2 f; };
union H8 { __half2 h[4]; float4 f; };

// u32 byte-offset gather helpers (enables s[base]+v[u32] addressing)
__device__ __forceinline__ __half2 ldg_h2(const __half* base, unsigned byteoff){
  return *(const __half2*)((const char*)base + byteoff);
}
__device__ __forceinline__ float ldg_f(const float* base, unsigned byteoff){
  return *(const float*)((const char*)base + byteoff);
}
__device__ __forceinline__ float2 ldg_f2(const float2* base, unsigned byteoff){
  return *(const float2*)((const char*)base + byteoff);
}

// ---------------- CSR build ----------------
__global__ void k_deg(const int* __restrict__ dst, int* __restrict__ deg){
  int i = blockIdx.x * blockDim.x + threadIdx.x;
  if (i < N_EDGES) atomicAdd(&deg[dst[i]], 1);
}

// parallel scan: A) block sums  B) scan of block sums (+ prew dot-vectors)  C) scatter
__global__ __launch_bounds__(256) void k_scan_a(const int* __restrict__ deg, int* __restrict__ bsum){
  __shared__ int ws[4];
  int b = blockIdx.x, t = threadIdx.x, i = b * 256 + t;
  int x = (i < N_NODES) ? deg[i] : 0;
  #pragma unroll
  for (int off = 32; off; off >>= 1) x += __shfl_down(x, off, 64);
  if ((t & 63) == 0) ws[t >> 6] = x;
  __syncthreads();
  if (t == 0) bsum[b] = ws[0] + ws[1] + ws[2] + ws[3];
}

__global__ __launch_bounds__(256) void k_scan_b(int* __restrict__ bsum, int nb,
      const float* __restrict__ W2, const float* __restrict__ W3,
      const float* __restrict__ a2s, const float* __restrict__ a2d,
      const float* __restrict__ a3s, const float* __restrict__ a3d,
      float* __restrict__ prew){
  __shared__ int ws[4];
  int t = threadIdx.x, lane = t & 63, wv = t >> 6;
  int x = (t < nb) ? bsum[t] : 0;
  #pragma unroll
  for (int off = 1; off < 64; off <<= 1){
    int y = __shfl_up(x, off, 64);
    if (lane >= off) x += y;
  }
  if (lane == 63) ws[wv] = x;
  __syncthreads();
  int add = 0;
  for (int w = 0; w < wv; ++w) add += ws[w];
  x += add;
  if (t < nb) bsum[t] = x;   // inclusive

  // prew: [w2s | w2d | w3s | w3d], each 64 floats. prew[vec*64+k] = sum_c W[k][c]*a[c]
  int vec = t >> 6, k = t & 63;
  const float* W = (vec < 2) ? W2 : W3;
  const float* a = (vec == 0) ? a2s : (vec == 1) ? a2d : (vec == 2) ? a3s : a3d;
  float s = 0.f;
  #pragma unroll 8
  for (int c = 0; c < D_OUTF; ++c) s = fmaf(W[k * D_OUTF + c], a[c], s);
  prew[t] = s;
}

__global__ __launch_bounds__(256) void k_scan_c(const int* __restrict__ deg,
        const int* __restrict__ bsum, int* __restrict__ rowptr){
  __shared__ int ws[4];
  int b = blockIdx.x, t = threadIdx.x, i = b * 256 + t;
  int lane = t & 63, wv = t >> 6;
  int x = (i < N_NODES) ? deg[i] : 0;
  #pragma unroll
  for (int off = 1; off < 64; off <<= 1){
    int y = __shfl_up(x, off, 64);
    if (lane >= off) x += y;
  }
  if (lane == 63) ws[wv] = x;
  __syncthreads();
  int add = (b > 0) ? bsum[b - 1] : 0;
  for (int w = 0; w < wv; ++w) add += ws[w];
  x += add;
  if (i < N_NODES) rowptr[i + 1] = x;
  if (b == 0 && t == 0) rowptr[0] = 0;
}

// fill: CSR slot gets {src, original edge index}
__global__ void k_fill(const int* __restrict__ src, const int* __restrict__ dst,
                       const int* __restrict__ rowptr, int* __restrict__ wcount,
                       int2* __restrict__ srcs2){
  int i = blockIdx.x * blockDim.x + threadIdx.x;
  if (i < N_EDGES){
    int d = dst[i];
    int pos = rowptr[d] + atomicAdd(&wcount[d], 1);
    srcs2[pos] = make_int2(src[i], i);
  }
}

// ---------------- layer 1 GEMM: h1 = x@W1 (tiled, fp16 out), es1/ed1 dots ----------------
__global__ __launch_bounds__(256) void k_gemm1(const float* __restrict__ x,
        const float* __restrict__ W1,
        const float* __restrict__ a_src, const float* __restrict__ a_dst,
        __half* __restrict__ h1h, float* __restrict__ es, float* __restrict__ ed){
  __shared__ float xs[2][MT][KB + 4];
  __shared__ float ws[2][KB][D_HID];
  const int tid = threadIdx.x;
  const int tc  = tid & 15;
  const int tr  = tid >> 4;
  const int row0 = blockIdx.x * MT;

  const int lxr = tid >> 2;
  const int lxp = (tid & 3) << 2;
  const int gxrow = row0 + lxr;
  const bool xok = gxrow < N_NODES;
  const float* xbase = x + (size_t)gxrow * D_INF + lxp;
  const int lwr = tid >> 4;
  const int lwp = (tid & 15) << 2;
  const float* wbase = W1 + lwr * D_HID + lwp;

  float4 xv = xok ? *(const float4*)xbase : make_float4(0.f,0.f,0.f,0.f);
  float4 wv = *(const float4*)wbase;
  *(float4*)&xs[0][lxr][lxp] = xv;
  *(float4*)&ws[0][lwr][lwp] = wv;
  __syncthreads();

  float acc[4][4] = {};
  int b = 0;
  #pragma unroll 1
  for (int ks = 0; ks < D_INF / KB; ++ks){
    if (ks < D_INF / KB - 1){
      xv = xok ? *(const float4*)(xbase + (ks + 1) * KB) : make_float4(0.f,0.f,0.f,0.f);
      wv = *(const float4*)(wbase + (size_t)(ks + 1) * KB * D_HID);
    }
    #pragma unroll
    for (int k4 = 0; k4 < KB / 4; ++k4){
      float4 xr4[4];
      #pragma unroll
      for (int r = 0; r < 4; ++r)
        xr4[r] = *(float4*)&xs[b][(tr << 2) + r][k4 << 2];
      #pragma unroll
      for (int j = 0; j < 4; ++j){
        float4 w4 = *(float4*)&ws[b][(k4 << 2) + j][tc << 2];
        #pragma unroll
        for (int r = 0; r < 4; ++r){
          float xk = (j == 0) ? xr4[r].x : (j == 1) ? xr4[r].y : (j == 2) ? xr4[r].z : xr4[r].w;
          acc[r][0] = fmaf(xk, w4.x, acc[r][0]);
          acc[r][1] = fmaf(xk, w4.y, acc[r][1]);
          acc[r][2] = fmaf(xk, w4.z, acc[r][2]);
          acc[r][3] = fmaf(xk, w4.w, acc[r][3]);
        }
      }
    }
    if (ks < D_INF / KB - 1){
      *(float4*)&xs[b ^ 1][lxr][lxp] = xv;
      *(float4*)&ws[b ^ 1][lwr][lwp] = wv;
    }
    __syncthreads();
    b ^= 1;
  }

  float as0 = a_src[tc << 2], as1 = a_src[(tc << 2) + 1],
        as2 = a_src[(tc << 2) + 2], as3 = a_src[(tc << 2) + 3];
  float ad0 = a_dst[tc << 2], ad1 = a_dst[(tc << 2) + 1],
        ad2 = a_dst[(tc << 2) + 2], ad3 = a_dst[(tc << 2) + 3];
  #pragma unroll
  for (int r = 0; r < 4; ++r){
    int row = row0 + (tr << 2) + r;
    float ps = acc[r][0]*as0 + acc[r][1]*as1 + acc[r][2]*as2 + acc[r][3]*as3;
    float pd = acc[r][0]*ad0 + acc[r][1]*ad1 + acc[r][2]*ad2 + acc[r][3]*ad3;
    #pragma unroll
    for (int off = 1; off < 16; off <<= 1){
      ps += __shfl_xor(ps, off, 64);
      pd += __shfl_xor(pd, off, 64);
    }
    if (row < N_NODES){
      H4 u;
      u.h[0] = __floats2half2_rn(acc[r][0], acc[r][1]);
      u.h[1] = __floats2half2_rn(acc[r][2], acc[r][3]);
      *(float2*)&h1h[(size_t)row * D_HID + (tc << 2)] = u.f;
      if (tc == 0){ es[row] = ps; ed[row] = pd; }
    }
  }
}

// ------- layer 1 aggregation (R6 structure) + bias + ELU + attention-dot scalars -------
__global__ __launch_bounds__(256) void k_agg1(const int* __restrict__ rowptr,
      const int2* __restrict__ srcs2,
      const __half* __restrict__ h1h, const float* __restrict__ es,
      const float* __restrict__ ed, const float* __restrict__ b1,
      const float* __restrict__ prew,
      __half* __restrict__ h1acth, float2* __restrict__ es23,
      float2* __restrict__ edinv2, float* __restrict__ ed3){
  int t = threadIdx.x, lane = t & 63, wv = t >> 6;
  int eslot = lane >> 5, c2 = lane & 31;

  int node = blockIdx.x * 4 + wv;
  int beg = rowptr[node], end = rowptr[node + 1];
  float edv = ed[node];
  float2 a0 = {0,0}, a1 = {0,0}, a2 = {0,0}, a3 = {0,0};
  float ss = 0.f;
  for (int i = beg; i < end; i += 16){
    int sA[8]; float2 v[8]; float p[8];
    int eb = i + (eslot << 3);
    #pragma unroll
    for (int u = 0; u < 8; ++u){
      int idx = eb + u;
      sA[u] = srcs2[(idx < end) ? idx : beg].x;
    }
    #pragma unroll
    for (int u = 0; u < 8; ++u)
      v[u] = __half22float2(ldg_h2(h1h, (unsigned)(sA[u] * 128 + (c2 << 2))));
    #pragma unroll
    for (int u = 0; u < 8; ++u){
      float e = __expf(leaky_relu(ldg_f(es, (unsigned)(sA[u] << 2)) + edv));
      p[u] = (eb + u < end) ? e : 0.f;
    }
    #pragma unroll
    for (int u = 0; u < 8; ++u){
      ss += p[u];
      float2* a = (u & 3) == 0 ? &a0 : (u & 3) == 1 ? &a1 : (u & 3) == 2 ? &a2 : &a3;
      a->x = fmaf(p[u], v[u].x, a->x);
      a->y = fmaf(p[u], v[u].y, a->y);
    }
  }
  float2 acc2;
  acc2.x = (a0.x + a1.x) + (a2.x + a3.x);
  acc2.y = (a0.y + a1.y) + (a2.y + a3.y);
  acc2.x += __shfl_xor(acc2.x, 32, 64);   // merge halves
  acc2.y += __shfl_xor(acc2.y, 32, 64);
  ss    += __shfl_xor(ss, 32, 64);

  float inv = 1.f / (ss + 1e-16f);
  float2 b1v = *(const float2*)&b1[c2 << 1];
  float ox = acc2.x * inv + b1v.x;
  float oy = acc2.y * inv + b1v.y;
  float2 hv;
  hv.x = ox > 0.f ? ox : expm1f(ox);
  hv.y = oy > 0.f ? oy : expm1f(oy);      // h1act channels 2c2, 2c2+1 (both halves identical)

  if (eslot == 0){
    H4 u; u.h[0] = __floats2half2_rn(hv.x, hv.y);
    *(__half2*)&h1acth[(size_t)node * D_HID + (c2 << 1)] = u.h[0];
  }

  // attention-dot scalars: half0 -> layer2 (es2, ed2), half1 -> layer3 (es3, ed3)
  const float* pb = prew + (eslot ? 128 : 0);
  float2 wsv = *(const float2*)&pb[c2 << 1];
  float2 wdv = *(const float2*)&pb[64 + (c2 << 1)];
  float psum = hv.x * wsv.x + hv.y * wsv.y;
  float pdum = hv.x * wdv.x + hv.y * wdv.y;
  #pragma unroll
  for (int off = 1; off < 32; off <<= 1){
    psum += __shfl_xor(psum, off, 64);
    pdum += __shfl_xor(pdum, off, 64);
  }
  if (c2 == 0){
    if (eslot){ es23[node].y = psum; ed3[node] = pdum; }
    else      { es23[node].x = psum; edinv2[node].x = pdum; }
  }
}

// ---------------- dense GEMM: h23 = h1act(fp16) @ [W2 | W3] -> fp16 ----------------
__global__ __launch_bounds__(256) void k_gemm23(const __half* __restrict__ h1acth,
        const float* __restrict__ W2, const float* __restrict__ W3,
        __half* __restrict__ h23h){
  __shared__ float hs[64][68];
  __shared__ float wsd[64][64];
  const int tid = threadIdx.x;
  const int row0 = blockIdx.x * 64;

  {
    int r = tid >> 2, cg = tid & 3;
    int grow = row0 + r;
    bool ok = grow < N_NODES;
    const float4* hrow = (const float4*)(h1acth + (size_t)grow * D_HID + cg * 16);
    H8 q0, q1;
    q0.f = ok ? hrow[0] : make_float4(0,0,0,0);
    q1.f = ok ? hrow[1] : make_float4(0,0,0,0);
    float* dsth = &hs[r][cg * 16];
    #pragma unroll
    for (int j = 0; j < 4; ++j){
      float2 f = __half22float2(q0.h[j]);
      dsth[j * 2] = f.x; dsth[j * 2 + 1] = f.y;
    }
    #pragma unroll
    for (int j = 0; j < 4; ++j){
      float2 f = __half22float2(q1.h[j]);
      dsth[8 + j * 2] = f.x; dsth[8 + j * 2 + 1] = f.y;
    }
    int k = tid >> 2;
    const float* Wsrc = (cg < 2) ? W2 : W3;
    int cbase = (cg & 1) * 16;
    float4* dstw = (float4*)&wsd[k][cg * 16];
    const float4* srcw = (const float4*)&Wsrc[k * D_OUTF + cbase];
    #pragma unroll
    for (int j = 0; j < 4; ++j) dstw[j] = srcw[j];
  }
  __syncthreads();

  const int tc = tid & 15, tr = tid >> 4;
  float acc[4][4] = {};
  #pragma unroll
  for (int k4 = 0; k4 < 16; ++k4){
    float4 xr4[4];
    #pragma unroll
    for (int r = 0; r < 4; ++r)
      xr4[r] = *(float4*)&hs[(tr << 2) + r][k4 << 2];
    #pragma unroll
    for (int j = 0; j < 4; ++j){
      float4 w4 = *(float4*)&wsd[(k4 << 2) + j][tc << 2];
      #pragma unroll
      for (int r = 0; r < 4; ++r){
        float xk = (j == 0) ? xr4[r].x : (j == 1) ? xr4[r].y : (j == 2) ? xr4[r].z : xr4[r].w;
        acc[r][0] = fmaf(xk, w4.x, acc[r][0]);
        acc[r][1] = fmaf(xk, w4.y, acc[r][1]);
        acc[r][2] = fmaf(xk, w4.z, acc[r][2]);
        acc[r][3] = fmaf(xk, w4.w, acc[r][3]);
      }
    }
  }
  #pragma unroll
  for (int r = 0; r < 4; ++r){
    int row = row0 + (tr << 2) + r;
    if (row < N_NODES){
      H4 u;
      u.h[0] = __floats2half2_rn(acc[r][0], acc[r][1]);
      u.h[1] = __floats2half2_rn(acc[r][2], acc[r][3]);
      *(float2*)&h23h[(size_t)row * 64 + (tc << 2)] = u.f;
    }
  }
}

// ------- layers 2&3 aggregation (R6 structure) + relu + linear + var + FUSED alpha -------
__global__ __launch_bounds__(256) void k_agg23(const int* __restrict__ rowptr,
   const int2* __restrict__ srcs2,
   const __half* __restrict__ h23h,
   const float2* __restrict__ es23, const float2* __restrict__ edinv2,
   const float* __restrict__ ed3,
   const float* __restrict__ b2, const float* __restrict__ b3,
   const float* __restrict__ Wlin, const float* __restrict__ blin,
   float* __restrict__ mean_out, float* __restrict__ var_out,
   float* __restrict__ alpha_out){
  __shared__ float sWl[D_OUTF * D_OUTF];
  int t = threadIdx.x, lane = t & 63, wv = t >> 6;
  int eslot = lane >> 5, c2 = lane & 31;
  int layer = c2 >> 4;                   // 0: layer-2 (mean), 1: layer-3 (var)
  int cc = (c2 & 15) << 1;               // channel pair within the 32-wide output
  for (int idx = t; idx < D_OUTF * D_OUTF; idx += 256) sWl[idx] = Wlin[idx];
  __syncthreads();

  int node = blockIdx.x * 4 + wv;
  int beg = rowptr[node], end = rowptr[node + 1];
  float edv = layer ? ed3[node] : edinv2[node].x;
  float2 a0 = {0,0}, a1 = {0,0}, a2 = {0,0}, a3 = {0,0};
  float ss = 0.f;
  for (int i = beg; i < end; i += 16){
    int sA[8]; float2 v[8]; float p[8];
    int eb = i + (eslot << 3);
    #pragma unroll
    for (int u = 0; u < 8; ++u){
      int idx = eb + u;
      sA[u] = srcs2[(idx < end) ? idx : beg].x;
    }
    #pragma unroll
    for (int u = 0; u < 8; ++u)
      v[u] = __half22float2(ldg_h2(h23h, (unsigned)(sA[u] * 128 + (c2 << 2))));
    #pragma unroll
    for (int u = 0; u < 8; ++u){
      float2 e2 = ldg_f2(es23, (unsigned)(sA[u] << 3));
      float esv = layer ? e2.y : e2.x;
      float e = __expf(leaky_relu(esv + edv));
      p[u] = (eb + u < end) ? e : 0.f;
    }
    #pragma unroll
    for (int u = 0; u < 8; ++u){
      ss += p[u];
      float2* a = (u & 3) == 0 ? &a0 : (u & 3) == 1 ? &a1 : (u & 3) == 2 ? &a2 : &a3;
      a->x = fmaf(p[u], v[u].x, a->x);
      a->y = fmaf(p[u], v[u].y, a->y);
    }
  }
  float2 acc2;
  acc2.x = (a0.x + a1.x) + (a2.x + a3.x);
  acc2.y = (a0.y + a1.y) + (a2.y + a3.y);
  acc2.x += __shfl_xor(acc2.x, 32, 64);
  acc2.y += __shfl_xor(acc2.y, 32, 64);
  ss    += __shfl_xor(ss, 32, 64);

  if (layer){  // layer-3 self loop
    float ps = __expf(leaky_relu(es23[node].y + ed3[node]));
    ss += ps;
    float2 hv = __half22float2(*(const __half2*)&h23h[(size_t)node * 64 + (c2 << 1)]);
    acc2.x = fmaf(ps, hv.x, acc2.x);
    acc2.y = fmaf(ps, hv.y, acc2.y);
  }
  float inv = 1.f / (ss + 1e-16f);
  if (layer){
    if (eslot == 0){
      float2 o = { acc2.x * inv + b3[cc], acc2.y * inv + b3[cc + 1] };
      *(float2*)&var_out[(size_t)node * D_OUTF + cc] = o;
    }
  } else {
    float2 mean;
    mean.x = acc2.x * inv + b2[cc];
    mean.y = acc2.y * inv + b2[cc + 1];
    mean.x = mean.x > 0.f ? mean.x : 0.f;
    mean.y = mean.y > 0.f ? mean.y : 0.f;
    float2 o = *(const float2*)&blin[cc];
    #pragma unroll
    for (int j2 = 0; j2 < 16; ++j2){
      float mjx = __shfl(mean.x, j2, 64);
      float mjy = __shfl(mean.y, j2, 64);
      float2 w0 = *(float2*)&sWl[(j2 * 2) * D_OUTF + cc];
      float2 w1 = *(float2*)&sWl[(j2 * 2 + 1) * D_OUTF + cc];
      o.x = fmaf(mjx, w0.x, o.x); o.x = fmaf(mjy, w1.x, o.x);
      o.y = fmaf(mjx, w0.y, o.y); o.y = fmaf(mjy, w1.y, o.y);
    }
    if (eslot == 0)
      *(float2*)&mean_out[(size_t)node * D_OUTF + cc] = o;
  }

  // fused alpha: all lanes, edges strided by 64; tables are L1/L2-hot from main loop
  float inv2all = __shfl(inv, 0, 64);   // lane 0 is layer-2
  float ed2all  = __shfl(edv, 0, 64);
  for (int i = beg + lane; i < end; i += 64){
    int2 se = srcs2[i];
    float p2 = __expf(leaky_relu(es23[se.x].x + ed2all));
    alpha_out[se.y] = p2 * inv2all;
  }
}

extern "C" void kernel_launch(void* const* d_in, const int* in_sizes, int n_in,
                              void* d_out, int out_size, void* d_ws, size_t ws_size,
                              hipStream_t stream) {
  const float* x   = (const float*)d_in[0];
  const int*   ei  = (const int*)d_in[1];
  const int*   src = ei;
  const int*   dst = ei + N_EDGES;
  const float* W1  = (const float*)d_in[2];
  const float* a1s = (const float*)d_in[3];
  const float* a1d = (const float*)d_in[4];
  const float* b1  = (const float*)d_in[5];
  const float* W2  = (const float*)d_in[6];
  const float* a2s = (const float*)d_in[7];
  const float* a2d = (const float*)d_in[8];
  const float* b2  = (const float*)d_in[9];
  const float* W3  = (const float*)d_in[10];
  const float* a3s = (const float*)d_in[11];
  const float* a3d = (const float*)d_in[12];
  const float* b3  = (const float*)d_in[13];
  const float* Wl  = (const float*)d_in[14];
  const float* bl  = (const float*)d_in[15];

  float* out       = (float*)d_out;
  float* mean_out  = out;
  float* var_out   = out + (size_t)N_NODES * D_OUTF;
  float* alpha_out = out + 2 * (size_t)N_NODES * D_OUTF;

  const int NSCAN = (N_NODES + 255) / 256;       // 196

  int* deg      = (int*)d_ws;                 // N
  int* wcount   = deg + N_NODES;              // N
  int* rowptr   = wcount + N_NODES;           // N+1
  int* bsum     = rowptr + (N_NODES + 1);     // NSCAN (+1 pad -> 8B align)
  int2* srcs2   = (int2*)(bsum + NSCAN + 1);  // E int2
  __half* h1h   = (__half*)(srcs2 + N_EDGES);
  __half* h1act = h1h + (size_t)N_NODES * 64;
  __half* h23h  = h1act + (size_t)N_NODES * 64;
  float* es1    = (float*)(h23h + (size_t)N_NODES * 64);
  float* ed1    = es1 + N_NODES;
  float* ed3    = ed1 + N_NODES;
  float* prew   = ed3 + N_NODES;              // 256 floats
  float2* es23  = (float2*)(prew + 256);
  float2* edinv2= es23 + N_NODES;

  hipMemsetAsync(deg, 0, 2 * (size_t)N_NODES * sizeof(int), stream);

  k_deg   <<<(N_EDGES + 255) / 256, 256, 0, stream>>>(dst, deg);
  k_scan_a<<<NSCAN, 256, 0, stream>>>(deg, bsum);
  k_scan_b<<<1, 256, 0, stream>>>(bsum, NSCAN, W2, W3, a2s, a2d, a3s, a3d, prew);
  k_scan_c<<<NSCAN, 256, 0, stream>>>(deg, bsum, rowptr);
  k_fill  <<<(N_EDGES + 255) / 256, 256, 0, stream>>>(src, dst, rowptr, wcount, srcs2);

  k_gemm1<<<(N_NODES + MT - 1) / MT, 256, 0, stream>>>(x, W1, a1s, a1d, h1h, es1, ed1);
  k_agg1 <<<N_NODES / 4, 256, 0, stream>>>(rowptr, srcs2, h1h, es1, ed1, b1, prew,
                                           h1act, es23, edinv2, ed3);
  k_gemm23<<<(N_NODES + 63) / 64, 256, 0, stream>>>(h1act, W2, W3, h23h);
  k_agg23<<<N_NODES / 4, 256, 0, stream>>>(rowptr, srcs2, h23h,
                                           es23, edinv2, ed3, b2, b3, Wl, bl,
                                           mean_out, var_out, alpha_out);
}

// Round 10
// 233.829 us; speedup vs baseline: 1.0764x; 1.0764x over previous
//
#include <hip/hip_runtime.h>
#include <hip/hip_fp16.h>
#include <math.h>

#define N_NODES 50000
#define N_EDGES 800000
#define D_INF   256
#define D_HID   64
#define D_OUTF  32
#define LEAKY   0.2f

#define MT 64     // gemm1 M-tile rows
#define KB 16     // gemm1 K-step

__device__ __forceinline__ float leaky_relu(float x){ return x >= 0.f ? x : LEAKY * x; }

union H4 { __half2 h[2]; float2 f; };
union H8 { __half2 h[4]; float4 f; };

// u32 byte-offset gather helpers (enables s[base]+v[u32] addressing)
__device__ __forceinline__ float2 ldg_raw8(const __half* base, unsigned byteoff){
  return *(const float2*)((const char*)base + byteoff);   // 4 halfs
}
__device__ __forceinline__ float ldg_f(const float* base, unsigned byteoff){
  return *(const float*)((const char*)base + byteoff);
}
__device__ __forceinline__ float2 ldg_f2(const float2* base, unsigned byteoff){
  return *(const float2*)((const char*)base + byteoff);
}

// ---------------- CSR build ----------------
__global__ void k_deg(const int* __restrict__ dst, int* __restrict__ deg,
                      int* __restrict__ rank){
  int i = blockIdx.x * blockDim.x + threadIdx.x;
  if (i < N_EDGES) rank[i] = atomicAdd(&deg[dst[i]], 1);
}

// parallel scan: A) block sums  B) scan of block sums (+ prew dot-vectors)  C) scatter
__global__ __launch_bounds__(256) void k_scan_a(const int* __restrict__ deg, int* __restrict__ bsum){
  __shared__ int ws[4];
  int b = blockIdx.x, t = threadIdx.x, i = b * 256 + t;
  int x = (i < N_NODES) ? deg[i] : 0;
  #pragma unroll
  for (int off = 32; off; off >>= 1) x += __shfl_down(x, off, 64);
  if ((t & 63) == 0) ws[t >> 6] = x;
  __syncthreads();
  if (t == 0) bsum[b] = ws[0] + ws[1] + ws[2] + ws[3];
}

__global__ __launch_bounds__(256) void k_scan_b(int* __restrict__ bsum, int nb,
      const float* __restrict__ W2, const float* __restrict__ W3,
      const float* __restrict__ a2s, const float* __restrict__ a2d,
      const float* __restrict__ a3s, const float* __restrict__ a3d,
      float* __restrict__ prew){
  __shared__ int ws[4];
  int t = threadIdx.x, lane = t & 63, wv = t >> 6;
  int x = (t < nb) ? bsum[t] : 0;
  #pragma unroll
  for (int off = 1; off < 64; off <<= 1){
    int y = __shfl_up(x, off, 64);
    if (lane >= off) x += y;
  }
  if (lane == 63) ws[wv] = x;
  __syncthreads();
  int add = 0;
  for (int w = 0; w < wv; ++w) add += ws[w];
  x += add;
  if (t < nb) bsum[t] = x;   // inclusive

  // prew: [w2s | w2d | w3s | w3d], each 64 floats. prew[vec*64+k] = sum_c W[k][c]*a[c]
  int vec = t >> 6, k = t & 63;
  const float* W = (vec < 2) ? W2 : W3;
  const float* a = (vec == 0) ? a2s : (vec == 1) ? a2d : (vec == 2) ? a3s : a3d;
  float s = 0.f;
  #pragma unroll 8
  for (int c = 0; c < D_OUTF; ++c) s = fmaf(W[k * D_OUTF + c], a[c], s);
  prew[t] = s;
}

__global__ __launch_bounds__(256) void k_scan_c(const int* __restrict__ deg,
        const int* __restrict__ bsum, int* __restrict__ rowptr){
  __shared__ int ws[4];
  int b = blockIdx.x, t = threadIdx.x, i = b * 256 + t;
  int lane = t & 63, wv = t >> 6;
  int x = (i < N_NODES) ? deg[i] : 0;
  #pragma unroll
  for (int off = 1; off < 64; off <<= 1){
    int y = __shfl_up(x, off, 64);
    if (lane >= off) x += y;
  }
  if (lane == 63) ws[wv] = x;
  __syncthreads();
  int add = (b > 0) ? bsum[b - 1] : 0;
  for (int w = 0; w < wv; ++w) add += ws[w];
  x += add;
  if (i < N_NODES) rowptr[i + 1] = x;
  if (b == 0 && t == 0) rowptr[0] = 0;
}

// fill: atomic-free (uses rank from k_deg)
__global__ void k_fill(const int* __restrict__ src, const int* __restrict__ dst,
                       const int* __restrict__ rowptr, const int* __restrict__ rank,
                       int* __restrict__ srcs, int* __restrict__ eidx){
  int i = blockIdx.x * blockDim.x + threadIdx.x;
  if (i < N_EDGES){
    int pos = rowptr[dst[i]] + rank[i];
    srcs[pos] = src[i];
    eidx[pos] = i;
  }
}

// ---------------- layer 1 GEMM: h1 = x@W1 (tiled, fp16 out), es1/ed1 dots ----------------
__global__ __launch_bounds__(256) void k_gemm1(const float* __restrict__ x,
        const float* __restrict__ W1,
        const float* __restrict__ a_src, const float* __restrict__ a_dst,
        __half* __restrict__ h1h, float* __restrict__ es, float* __restrict__ ed){
  __shared__ float xs[2][MT][KB + 4];
  __shared__ float ws[2][KB][D_HID];
  const int tid = threadIdx.x;
  const int tc  = tid & 15;
  const int tr  = tid >> 4;
  const int row0 = blockIdx.x * MT;

  const int lxr = tid >> 2;
  const int lxp = (tid & 3) << 2;
  const int gxrow = row0 + lxr;
  const bool xok = gxrow < N_NODES;
  const float* xbase = x + (size_t)gxrow * D_INF + lxp;
  const int lwr = tid >> 4;
  const int lwp = (tid & 15) << 2;
  const float* wbase = W1 + lwr * D_HID + lwp;

  float4 xv = xok ? *(const float4*)xbase : make_float4(0.f,0.f,0.f,0.f);
  float4 wv = *(const float4*)wbase;
  *(float4*)&xs[0][lxr][lxp] = xv;
  *(float4*)&ws[0][lwr][lwp] = wv;
  __syncthreads();

  float acc[4][4] = {};
  int b = 0;
  #pragma unroll 1
  for (int ks = 0; ks < D_INF / KB; ++ks){
    if (ks < D_INF / KB - 1){
      xv = xok ? *(const float4*)(xbase + (ks + 1) * KB) : make_float4(0.f,0.f,0.f,0.f);
      wv = *(const float4*)(wbase + (size_t)(ks + 1) * KB * D_HID);
    }
    #pragma unroll
    for (int k4 = 0; k4 < KB / 4; ++k4){
      float4 xr4[4];
      #pragma unroll
      for (int r = 0; r < 4; ++r)
        xr4[r] = *(float4*)&xs[b][(tr << 2) + r][k4 << 2];
      #pragma unroll
      for (int j = 0; j < 4; ++j){
        float4 w4 = *(float4*)&ws[b][(k4 << 2) + j][tc << 2];
        #pragma unroll
        for (int r = 0; r < 4; ++r){
          float xk = (j == 0) ? xr4[r].x : (j == 1) ? xr4[r].y : (j == 2) ? xr4[r].z : xr4[r].w;
          acc[r][0] = fmaf(xk, w4.x, acc[r][0]);
          acc[r][1] = fmaf(xk, w4.y, acc[r][1]);
          acc[r][2] = fmaf(xk, w4.z, acc[r][2]);
          acc[r][3] = fmaf(xk, w4.w, acc[r][3]);
        }
      }
    }
    if (ks < D_INF / KB - 1){
      *(float4*)&xs[b ^ 1][lxr][lxp] = xv;
      *(float4*)&ws[b ^ 1][lwr][lwp] = wv;
    }
    __syncthreads();
    b ^= 1;
  }

  float as0 = a_src[tc << 2], as1 = a_src[(tc << 2) + 1],
        as2 = a_src[(tc << 2) + 2], as3 = a_src[(tc << 2) + 3];
  float ad0 = a_dst[tc << 2], ad1 = a_dst[(tc << 2) + 1],
        ad2 = a_dst[(tc << 2) + 2], ad3 = a_dst[(tc << 2) + 3];
  #pragma unroll
  for (int r = 0; r < 4; ++r){
    int row = row0 + (tr << 2) + r;
    float ps = acc[r][0]*as0 + acc[r][1]*as1 + acc[r][2]*as2 + acc[r][3]*as3;
    float pd = acc[r][0]*ad0 + acc[r][1]*ad1 + acc[r][2]*ad2 + acc[r][3]*ad3;
    #pragma unroll
    for (int off = 1; off < 16; off <<= 1){
      ps += __shfl_xor(ps, off, 64);
      pd += __shfl_xor(pd, off, 64);
    }
    if (row < N_NODES){
      H4 u;
      u.h[0] = __floats2half2_rn(acc[r][0], acc[r][1]);
      u.h[1] = __floats2half2_rn(acc[r][2], acc[r][3]);
      *(float2*)&h1h[(size_t)row * D_HID + (tc << 2)] = u.f;
      if (tc == 0){ es[row] = ps; ed[row] = pd; }
    }
  }
}

// ------- layer 1 aggregation: 8B/lane (4 edges per wave-load, 32 in flight) -------
__global__ __launch_bounds__(256) void k_agg1(const int* __restrict__ rowptr,
      const int* __restrict__ srcs,
      const __half* __restrict__ h1h, const float* __restrict__ es,
      const float* __restrict__ ed, const float* __restrict__ b1,
      const float* __restrict__ prew,
      __half* __restrict__ h1acth, float2* __restrict__ es23,
      float2* __restrict__ edinv2, float* __restrict__ ed3){
  int t = threadIdx.x, lane = t & 63, wv = t >> 6;
  int slot = lane >> 4, cg = lane & 15;     // slot = edge sub-slot, cg = 4-channel group
  unsigned coff = cg << 3;                  // byte offset within 128B row

  int node = blockIdx.x * 4 + wv;
  int beg = rowptr[node], end = rowptr[node + 1];
  float edv = ed[node];
  float4 acc = {0.f,0.f,0.f,0.f};
  float ss = 0.f;
  for (int i = beg; i < end; i += 32){
    int sA[8]; float2 vr[8]; float p[8];
    #pragma unroll
    for (int u = 0; u < 8; ++u){
      int idx = i + (u << 2) + slot;
      sA[u] = srcs[idx < end ? idx : end - 1];
    }
    #pragma unroll
    for (int u = 0; u < 8; ++u)
      vr[u] = ldg_raw8(h1h, (unsigned)(sA[u] * 128) + coff);
    #pragma unroll
    for (int u = 0; u < 8; ++u){
      float e = __expf(leaky_relu(ldg_f(es, (unsigned)(sA[u] << 2)) + edv));
      p[u] = ((i + (u << 2) + slot) < end) ? e : 0.f;
    }
    #pragma unroll
    for (int u = 0; u < 8; ++u){
      ss += p[u];
      H4 hh; hh.f = vr[u];
      float2 lo = __half22float2(hh.h[0]);
      float2 hi = __half22float2(hh.h[1]);
      acc.x = fmaf(p[u], lo.x, acc.x);
      acc.y = fmaf(p[u], lo.y, acc.y);
      acc.z = fmaf(p[u], hi.x, acc.z);
      acc.w = fmaf(p[u], hi.y, acc.w);
    }
  }
  // merge the 4 edge slots (lane bits 4,5)
  #pragma unroll
  for (int off = 16; off <= 32; off <<= 1){
    acc.x += __shfl_xor(acc.x, off, 64);
    acc.y += __shfl_xor(acc.y, off, 64);
    acc.z += __shfl_xor(acc.z, off, 64);
    acc.w += __shfl_xor(acc.w, off, 64);
    ss    += __shfl_xor(ss,    off, 64);
  }
  float inv = 1.f / (ss + 1e-16f);
  float4 b4 = *(const float4*)&b1[cg << 2];
  float4 hv;
  hv.x = acc.x * inv + b4.x;  hv.x = hv.x > 0.f ? hv.x : expm1f(hv.x);
  hv.y = acc.y * inv + b4.y;  hv.y = hv.y > 0.f ? hv.y : expm1f(hv.y);
  hv.z = acc.z * inv + b4.z;  hv.z = hv.z > 0.f ? hv.z : expm1f(hv.z);
  hv.w = acc.w * inv + b4.w;  hv.w = hv.w > 0.f ? hv.w : expm1f(hv.w);

  if (slot == 0){
    H4 u2;
    u2.h[0] = __floats2half2_rn(hv.x, hv.y);
    u2.h[1] = __floats2half2_rn(hv.z, hv.w);
    *(float2*)&h1acth[(size_t)node * D_HID + (cg << 2)] = u2.f;
  }

  // attention-dot scalars: quarter q=slot computes one of {es2, ed2, es3, ed3}
  float4 w4 = *(const float4*)&prew[(slot << 6) + (cg << 2)];
  float part = hv.x * w4.x + hv.y * w4.y + hv.z * w4.z + hv.w * w4.w;
  #pragma unroll
  for (int off = 1; off < 16; off <<= 1) part += __shfl_xor(part, off, 64);
  if (cg == 0){
    if      (slot == 0) es23[node].x   = part;
    else if (slot == 1) edinv2[node].x = part;
    else if (slot == 2) es23[node].y   = part;
    else                ed3[node]      = part;
  }
}

// ---------------- dense GEMM: h23 = h1act(fp16) @ [W2 | W3] -> fp16 ----------------
__global__ __launch_bounds__(256) void k_gemm23(const __half* __restrict__ h1acth,
        const float* __restrict__ W2, const float* __restrict__ W3,
        __half* __restrict__ h23h){
  __shared__ float hs[64][68];
  __shared__ float wsd[64][64];
  const int tid = threadIdx.x;
  const int row0 = blockIdx.x * 64;

  {
    int r = tid >> 2, cg = tid & 3;
    int grow = row0 + r;
    bool ok = grow < N_NODES;
    const float4* hrow = (const float4*)(h1acth + (size_t)grow * D_HID + cg * 16);
    H8 q0, q1;
    q0.f = ok ? hrow[0] : make_float4(0,0,0,0);
    q1.f = ok ? hrow[1] : make_float4(0,0,0,0);
    float* dsth = &hs[r][cg * 16];
    #pragma unroll
    for (int j = 0; j < 4; ++j){
      float2 f = __half22float2(q0.h[j]);
      dsth[j * 2] = f.x; dsth[j * 2 + 1] = f.y;
    }
    #pragma unroll
    for (int j = 0; j < 4; ++j){
      float2 f = __half22float2(q1.h[j]);
      dsth[8 + j * 2] = f.x; dsth[8 + j * 2 + 1] = f.y;
    }
    int k = tid >> 2;
    const float* Wsrc = (cg < 2) ? W2 : W3;
    int cbase = (cg & 1) * 16;
    float4* dstw = (float4*)&wsd[k][cg * 16];
    const float4* srcw = (const float4*)&Wsrc[k * D_OUTF + cbase];
    #pragma unroll
    for (int j = 0; j < 4; ++j) dstw[j] = srcw[j];
  }
  __syncthreads();

  const int tc = tid & 15, tr = tid >> 4;
  float acc[4][4] = {};
  #pragma unroll
  for (int k4 = 0; k4 < 16; ++k4){
    float4 xr4[4];
    #pragma unroll
    for (int r = 0; r < 4; ++r)
      xr4[r] = *(float4*)&hs[(tr << 2) + r][k4 << 2];
    #pragma unroll
    for (int j = 0; j < 4; ++j){
      float4 w4 = *(float4*)&wsd[(k4 << 2) + j][tc << 2];
      #pragma unroll
      for (int r = 0; r < 4; ++r){
        float xk = (j == 0) ? xr4[r].x : (j == 1) ? xr4[r].y : (j == 2) ? xr4[r].z : xr4[r].w;
        acc[r][0] = fmaf(xk, w4.x, acc[r][0]);
        acc[r][1] = fmaf(xk, w4.y, acc[r][1]);
        acc[r][2] = fmaf(xk, w4.z, acc[r][2]);
        acc[r][3] = fmaf(xk, w4.w, acc[r][3]);
      }
    }
  }
  #pragma unroll
  for (int r = 0; r < 4; ++r){
    int row = row0 + (tr << 2) + r;
    if (row < N_NODES){
      H4 u;
      u.h[0] = __floats2half2_rn(acc[r][0], acc[r][1]);
      u.h[1] = __floats2half2_rn(acc[r][2], acc[r][3]);
      *(float2*)&h23h[(size_t)row * 64 + (tc << 2)] = u.f;
    }
  }
}

// ------- layers 2&3 aggregation: 8B/lane + relu + linear + var + fused alpha -------
__global__ __launch_bounds__(256) void k_agg23(const int* __restrict__ rowptr,
   const int* __restrict__ srcs, const int* __restrict__ eidx,
   const __half* __restrict__ h23h,
   const float2* __restrict__ es23, const float2* __restrict__ edinv2,
   const float* __restrict__ ed3,
   const float* __restrict__ b2, const float* __restrict__ b3,
   const float* __restrict__ Wlin, const float* __restrict__ blin,
   float* __restrict__ mean_out, float* __restrict__ var_out,
   float* __restrict__ alpha_out){
  __shared__ float sWl[D_OUTF * D_OUTF];
  int t = threadIdx.x, lane = t & 63, wv = t >> 6;
  int slot = lane >> 4, cg = lane & 15;
  int layerhi = cg >> 3;                 // 0: row ch 0-31 (layer2/mean), 1: ch 32-63 (layer3/var)
  unsigned coff = cg << 3;
  for (int idx = t; idx < D_OUTF * D_OUTF; idx += 256) sWl[idx] = Wlin[idx];
  __syncthreads();

  int node = blockIdx.x * 4 + wv;
  int beg = rowptr[node], end = rowptr[node + 1];
  float ed2v = edinv2[node].x;
  float ed3v = ed3[node];
  float edv = layerhi ? ed3v : ed2v;
  float4 acc = {0.f,0.f,0.f,0.f};
  float ss = 0.f;
  for (int i = beg; i < end; i += 32){
    int sA[8]; float2 vr[8]; float p[8];
    #pragma unroll
    for (int u = 0; u < 8; ++u){
      int idx = i + (u << 2) + slot;
      sA[u] = srcs[idx < end ? idx : end - 1];
    }
    #pragma unroll
    for (int u = 0; u < 8; ++u)
      vr[u] = ldg_raw8(h23h, (unsigned)(sA[u] * 128) + coff);
    #pragma unroll
    for (int u = 0; u < 8; ++u){
      float2 e2 = ldg_f2(es23, (unsigned)(sA[u] << 3));
      float esv = layerhi ? e2.y : e2.x;
      float e = __expf(leaky_relu(esv + edv));
      p[u] = ((i + (u << 2) + slot) < end) ? e : 0.f;
    }
    #pragma unroll
    for (int u = 0; u < 8; ++u){
      ss += p[u];
      H4 hh; hh.f = vr[u];
      float2 lo = __half22float2(hh.h[0]);
      float2 hi = __half22float2(hh.h[1]);
      acc.x = fmaf(p[u], lo.x, acc.x);
      acc.y = fmaf(p[u], lo.y, acc.y);
      acc.z = fmaf(p[u], hi.x, acc.z);
      acc.w = fmaf(p[u], hi.y, acc.w);
    }
  }
  #pragma unroll
  for (int off = 16; off <= 32; off <<= 1){
    acc.x += __shfl_xor(acc.x, off, 64);
    acc.y += __shfl_xor(acc.y, off, 64);
    acc.z += __shfl_xor(acc.z, off, 64);
    acc.w += __shfl_xor(acc.w, off, 64);
    ss    += __shfl_xor(ss,    off, 64);
  }

  if (layerhi){  // layer-3 self loop
    float ps = __expf(leaky_relu(es23[node].y + ed3v));
    ss += ps;
    H4 hh; hh.f = ldg_raw8(h23h, (unsigned)(node * 128) + coff);
    float2 lo = __half22float2(hh.h[0]);
    float2 hi = __half22float2(hh.h[1]);
    acc.x = fmaf(ps, lo.x, acc.x);
    acc.y = fmaf(ps, lo.y, acc.y);
    acc.z = fmaf(ps, hi.x, acc.z);
    acc.w = fmaf(ps, hi.y, acc.w);
  }
  float inv = 1.f / (ss + 1e-16f);
  if (layerhi){
    if (slot == 0){   // lanes 8-15: var channels (cg-8)*4..+3
      float4 b4 = *(const float4*)&b3[(cg & 7) << 2];
      float4 o = { acc.x * inv + b4.x, acc.y * inv + b4.y,
                   acc.z * inv + b4.z, acc.w * inv + b4.w };
      *(float4*)&var_out[(size_t)node * D_OUTF + ((cg & 7) << 2)] = o;
    }
  } else {
    float4 b4 = *(const float4*)&b2[cg << 2];
    float4 mean = { acc.x * inv + b4.x, acc.y * inv + b4.y,
                    acc.z * inv + b4.z, acc.w * inv + b4.w };
    mean.x = mean.x > 0.f ? mean.x : 0.f;
    mean.y = mean.y > 0.f ? mean.y : 0.f;
    mean.z = mean.z > 0.f ? mean.z : 0.f;
    mean.w = mean.w > 0.f ? mean.w : 0.f;
    // final linear: mean channels live on lanes 0-7 (slot0); shuffle-broadcast them
    float4 o = *(const float4*)&blin[(cg & 7) << 2];
    #pragma unroll
    for (int sl = 0; sl < 8; ++sl){
      float mx = __shfl(mean.x, sl, 64);
      float my = __shfl(mean.y, sl, 64);
      float mz = __shfl(mean.z, sl, 64);
      float mw = __shfl(mean.w, sl, 64);
      float4 r0 = *(float4*)&sWl[(4*sl + 0) * D_OUTF + ((cg & 7) << 2)];
      float4 r1 = *(float4*)&sWl[(4*sl + 1) * D_OUTF + ((cg & 7) << 2)];
      float4 r2 = *(float4*)&sWl[(4*sl + 2) * D_OUTF + ((cg & 7) << 2)];
      float4 r3 = *(float4*)&sWl[(4*sl + 3) * D_OUTF + ((cg & 7) << 2)];
      o.x = fmaf(mx, r0.x, o.x); o.y = fmaf(mx, r0.y, o.y); o.z = fmaf(mx, r0.z, o.z); o.w = fmaf(mx, r0.w, o.w);
      o.x = fmaf(my, r1.x, o.x); o.y = fmaf(my, r1.y, o.y); o.z = fmaf(my, r1.z, o.z); o.w = fmaf(my, r1.w, o.w);
      o.x = fmaf(mz, r2.x, o.x); o.y = fmaf(mz, r2.y, o.y); o.z = fmaf(mz, r2.z, o.z); o.w = fmaf(mz, r2.w, o.w);
      o.x = fmaf(mw, r3.x, o.x); o.y = fmaf(mw, r3.y, o.y); o.z = fmaf(mw, r3.z, o.z); o.w = fmaf(mw, r3.w, o.w);
    }
    if (slot == 0)    // lanes 0-7
      *(float4*)&mean_out[(size_t)node * D_OUTF + (cg << 2)] = o;
  }

  // fused alpha: all lanes, edges strided by 64 (srcs/es23 L2-hot from main loop)
  float inv2all = __shfl(inv, 0, 64);   // lane 0 holds layer-2 inv
  for (int i = beg + lane; i < end; i += 64){
    int s = srcs[i];
    float p2 = __expf(leaky_relu(es23[s].x + ed2v));
    alpha_out[eidx[i]] = p2 * inv2all;
  }
}

extern "C" void kernel_launch(void* const* d_in, const int* in_sizes, int n_in,
                              void* d_out, int out_size, void* d_ws, size_t ws_size,
                              hipStream_t stream) {
  const float* x   = (const float*)d_in[0];
  const int*   ei  = (const int*)d_in[1];
  const int*   src = ei;
  const int*   dst = ei + N_EDGES;
  const float* W1  = (const float*)d_in[2];
  const float* a1s = (const float*)d_in[3];
  const float* a1d = (const float*)d_in[4];
  const float* b1  = (const float*)d_in[5];
  const float* W2  = (const float*)d_in[6];
  const float* a2s = (const float*)d_in[7];
  const float* a2d = (const float*)d_in[8];
  const float* b2  = (const float*)d_in[9];
  const float* W3  = (const float*)d_in[10];
  const float* a3s = (const float*)d_in[11];
  const float* a3d = (const float*)d_in[12];
  const float* b3  = (const float*)d_in[13];
  const float* Wl  = (const float*)d_in[14];
  const float* bl  = (const float*)d_in[15];

  float* out       = (float*)d_out;
  float* mean_out  = out;
  float* var_out   = out + (size_t)N_NODES * D_OUTF;
  float* alpha_out = out + 2 * (size_t)N_NODES * D_OUTF;

  const int NSCAN = (N_NODES + 255) / 256;       // 196

  int* deg      = (int*)d_ws;                 // N
  int* rowptr   = deg + N_NODES;              // N+1
  int* bsum     = rowptr + (N_NODES + 1);     // NSCAN
  int* rank     = bsum + NSCAN;               // E
  int* srcs     = rank + N_EDGES;             // E
  int* eidx     = srcs + N_EDGES;             // E
  __half* h1h   = (__half*)(eidx + N_EDGES + 1);   // pad -> 8B aligned
  __half* h1act = h1h + (size_t)N_NODES * 64;
  __half* h23h  = h1act + (size_t)N_NODES * 64;
  float* es1    = (float*)(h23h + (size_t)N_NODES * 64);
  float* ed1    = es1 + N_NODES;
  float* ed3    = ed1 + N_NODES;
  float* prew   = ed3 + N_NODES;              // 256 floats
  float2* es23  = (float2*)(prew + 256);
  float2* edinv2= es23 + N_NODES;

  hipMemsetAsync(deg, 0, (size_t)N_NODES * sizeof(int), stream);

  k_deg   <<<(N_EDGES + 255) / 256, 256, 0, stream>>>(dst, deg, rank);
  k_scan_a<<<NSCAN, 256, 0, stream>>>(deg, bsum);
  k_scan_b<<<1, 256, 0, stream>>>(bsum, NSCAN, W2, W3, a2s, a2d, a3s, a3d, prew);
  k_scan_c<<<NSCAN, 256, 0, stream>>>(deg, bsum, rowptr);
  k_fill  <<<(N_EDGES + 255) / 256, 256, 0, stream>>>(src, dst, rowptr, rank, srcs, eidx);

  k_gemm1<<<(N_NODES + MT - 1) / MT, 256, 0, stream>>>(x, W1, a1s, a1d, h1h, es1, ed1);
  k_agg1 <<<N_NODES / 4, 256, 0, stream>>>(rowptr, srcs, h1h, es1, ed1, b1, prew,
                                           h1act, es23, edinv2, ed3);
  k_gemm23<<<(N_NODES + 63) / 64, 256, 0, stream>>>(h1act, W2, W3, h23h);
  k_agg23<<<N_NODES / 4, 256, 0, stream>>>(rowptr, srcs, eidx, h23h,
                                           es23, edinv2, ed3, b2, b3, Wl, bl,
                                           mean_out, var_out, alpha_out);
}